// Round 1
// baseline (382.865 us; speedup 1.0000x reference)
//
#include <hip/hip_runtime.h>

// Problem: N=4096, D=1024, C=1000, T=32
//   h = x @ W^T  (4096 x 2000), mu = h[:, :1000], logvar = h[:, 1000:]
//   sigma = exp(0.5*logvar)
//   eps = jax.random.normal(key(42), (32,4096,1000))  -- threefry2x32, must match bit-exactly
//   prob = mean_t softmax(mu + sigma*eps), out0 = exp(prob), out1 = sigma

typedef __attribute__((ext_vector_type(8))) short bf16x8;
typedef __attribute__((ext_vector_type(4))) float f32x4;

#define C_DIM   1000
#define NC_TOT  4096000
#define H_HALF  65536000u   // half of T*N*C = 131072000

// ---------------- fp32 -> bf16 (RNE) ----------------
__device__ __forceinline__ unsigned short f2bf(float f) {
  unsigned int u = __builtin_bit_cast(unsigned int, f);
  u += 0x7fffu + ((u >> 16) & 1u);
  return (unsigned short)(u >> 16);
}

// x: 4096x1024 fp32 -> xbf (bf16); W: 2000x1024 fp32 -> wbf padded to 2048 rows (zeros)
__global__ __launch_bounds__(256) void convert_kernel(
    const float* __restrict__ x, const float* __restrict__ W,
    unsigned short* __restrict__ xbf, unsigned short* __restrict__ wbf) {
  int qid = blockIdx.x * 256 + threadIdx.x;   // one float4 per thread
  if (qid < 1048576) {                        // x: 4096*1024/4
    float4 v = ((const float4*)x)[qid];
    ushort4 o = make_ushort4(f2bf(v.x), f2bf(v.y), f2bf(v.z), f2bf(v.w));
    ((ushort4*)xbf)[qid] = o;
  } else {
    int q = qid - 1048576;                    // padded W quad index, < 524288
    int row = q >> 8;                         // (q*4)>>10
    ushort4 o;
    if (row < 2000) {
      float4 v = ((const float4*)W)[q];       // same flat layout (stride 1024)
      o = make_ushort4(f2bf(v.x), f2bf(v.y), f2bf(v.z), f2bf(v.w));
    } else {
      o = make_ushort4(0, 0, 0, 0);
    }
    ((ushort4*)wbf)[q] = o;
  }
}

// ---------------- bf16 MFMA GEMM: h = x @ W^T ----------------
// 128x128 tile, BK=32, 256 thr = 4 waves, each wave 64x64 = 4x4 MFMA 16x16x32 tiles.
// Epilogue: c<1000 -> mu (ws), 1000<=c<2000 -> sigma = exp(0.5*h) into d_out+NC.
#define BK  32
#define LDK 40   // padded LDS k-stride (elems): 80B rows, breaks 4-way conflicts

__global__ __launch_bounds__(256) void gemm_kernel(
    const unsigned short* __restrict__ Abf,   // [4096][1024]
    const unsigned short* __restrict__ Bbf,   // [2048][1024] padded
    float* __restrict__ mu,                   // [4096][1000]
    float* __restrict__ sigma_out) {          // d_out + NC_TOT
  const int K = 1024;
  __shared__ unsigned short As[128 * LDK];
  __shared__ unsigned short Bs[128 * LDK];

  int tid  = threadIdx.x;
  int bx   = blockIdx.x;          // 0..15 (col tiles, padded N=2048)
  int by   = blockIdx.y;          // 0..31 (row tiles, M=4096)
  int w    = tid >> 6;
  int lane = tid & 63;
  int wr   = (w >> 1) * 64;       // wave row offset in tile
  int wc   = (w & 1) * 64;        // wave col offset in tile
  int lrow = lane & 15;
  int kq   = lane >> 4;           // 0..3, k-group of 8

  f32x4 acc[4][4];
  for (int i = 0; i < 4; i++)
    for (int j = 0; j < 4; j++) acc[i][j] = (f32x4){0.f, 0.f, 0.f, 0.f};

  int srow = tid >> 2;            // 0..63 staging row
  int sq   = tid & 3;             // staging k-group
  int aBase = (by * 128) * K;
  int bBase = (bx * 128) * K;

  for (int kk = 0; kk < K; kk += BK) {
    uint4 av0 = *(const uint4*)(Abf + aBase + srow * K        + kk + sq * 8);
    uint4 av1 = *(const uint4*)(Abf + aBase + (srow + 64) * K + kk + sq * 8);
    uint4 bv0 = *(const uint4*)(Bbf + bBase + srow * K        + kk + sq * 8);
    uint4 bv1 = *(const uint4*)(Bbf + bBase + (srow + 64) * K + kk + sq * 8);
    __syncthreads();   // previous iteration's LDS reads done
    *(uint4*)(As + srow * LDK        + sq * 8) = av0;
    *(uint4*)(As + (srow + 64) * LDK + sq * 8) = av1;
    *(uint4*)(Bs + srow * LDK        + sq * 8) = bv0;
    *(uint4*)(Bs + (srow + 64) * LDK + sq * 8) = bv1;
    __syncthreads();

    bf16x8 a[4], b[4];
    for (int i = 0; i < 4; i++)
      a[i] = *(const bf16x8*)(As + (wr + i * 16 + lrow) * LDK + kq * 8);
    for (int j = 0; j < 4; j++)
      b[j] = *(const bf16x8*)(Bs + (wc + j * 16 + lrow) * LDK + kq * 8);
    for (int i = 0; i < 4; i++)
      for (int j = 0; j < 4; j++)
        acc[i][j] = __builtin_amdgcn_mfma_f32_16x16x32_bf16(a[i], b[j], acc[i][j], 0, 0, 0);
  }

  // epilogue: C/D layout col = lane&15 (N), row = (lane>>4)*4 + reg (M)  [m89-verified]
  int orow0 = by * 128 + wr + (lane >> 4) * 4;
  int ocol0 = bx * 128 + wc + (lane & 15);
  for (int i = 0; i < 4; i++) {
    for (int j = 0; j < 4; j++) {
      int c = ocol0 + j * 16;
      for (int v = 0; v < 4; v++) {
        int r = orow0 + i * 16 + v;
        float val = acc[i][j][v];
        if (c < 1000)       mu[r * 1000 + c] = val;
        else if (c < 2000)  sigma_out[r * 1000 + (c - 1000)] = __expf(0.5f * val);
      }
    }
  }
}

// ---------------- threefry2x32, key = (0, 42) ----------------
__device__ __forceinline__ void threefry(unsigned x0, unsigned x1,
                                         unsigned& o0, unsigned& o1) {
  const unsigned ks1 = 42u;
  const unsigned ks2 = 0x1BD11BDAu ^ 42u;   // 0x1BD11BF0
#define TF_RND(r) { x0 += x1; x1 = (x1 << (r)) | (x1 >> (32 - (r))); x1 ^= x0; }
  /* x0 += ks0 (=0) */  x1 += ks1;
  TF_RND(13) TF_RND(15) TF_RND(26) TF_RND(6)
  x0 += ks1;  x1 += ks2 + 1u;
  TF_RND(17) TF_RND(29) TF_RND(16) TF_RND(24)
  x0 += ks2;  x1 += 2u;               // ks0 + 2
  TF_RND(13) TF_RND(15) TF_RND(26) TF_RND(6)
  /* x0 += ks0 */  x1 += ks1 + 3u;
  TF_RND(17) TF_RND(29) TF_RND(16) TF_RND(24)
  x0 += ks1;  x1 += ks2 + 4u;
  TF_RND(13) TF_RND(15) TF_RND(26) TF_RND(6)
  x0 += ks2;  x1 += 5u;               // ks0 + 5
#undef TF_RND
  o0 = x0; o1 = x1;
}

// bits -> uniform(-0.99999994, 1.0), exactly as JAX _uniform (scale folds to 2.0f)
__device__ __forceinline__ float bits_to_u(unsigned b) {
  unsigned fb = (b >> 9) | 0x3f800000u;
  float f = __builtin_bit_cast(float, fb) - 1.0f;   // [0, 1)
  float u = fmaf(f, 2.0f, -0.99999994f);            // f*2 exact -> identical to mul+add
  return fmaxf(-0.99999994f, u);
}

// sqrt(2) * erfinv(u), XLA ErfInv32 (Giles) coefficients
__device__ __forceinline__ float normal_from_u(float x) {
  float w = -__logf(fmaf(-x, x, 1.0f));   // -log1p(-x*x)
  float p;
  if (w < 5.0f) {
    float v = w - 2.5f;
    p = 2.81022636e-08f;
    p = fmaf(p, v, 3.43273939e-07f);
    p = fmaf(p, v, -3.5233877e-06f);
    p = fmaf(p, v, -4.39150654e-06f);
    p = fmaf(p, v, 0.00021858087f);
    p = fmaf(p, v, -0.00125372503f);
    p = fmaf(p, v, -0.00417768164f);
    p = fmaf(p, v, 0.246640727f);
    p = fmaf(p, v, 1.50140941f);
  } else {
    float v = __fsqrt_rn(w) - 3.0f;
    p = -0.000200214257f;
    p = fmaf(p, v, 0.000100950558f);
    p = fmaf(p, v, 0.00134934322f);
    p = fmaf(p, v, -0.00367342844f);
    p = fmaf(p, v, 0.00573950773f);
    p = fmaf(p, v, -0.0076224613f);
    p = fmaf(p, v, 0.00943887047f);
    p = fmaf(p, v, 1.00167406f);
    p = fmaf(p, v, 2.83297682f);
  }
  return 1.41421356f * (p * x);
}

// ---------------- sampling: one block per row n ----------------
// flat eps idx = t*4096000 + n*1000 + c ; pair (i, i+H) gives eps(t) and eps(t+16)
__global__ __launch_bounds__(256) void sample_kernel(
    const float* __restrict__ mu,      // ws
    const float* __restrict__ sigma,   // d_out + NC
    float* __restrict__ out0) {        // d_out
  int n   = blockIdx.x;
  int tid = threadIdx.x;
  int lane = tid & 63, w = tid >> 6;
  __shared__ float redA[4], redB[4];

  float muv[4], sgv[4], prob[4];
  bool valid[4];
  int cbase = n * 1000;
  for (int k = 0; k < 4; k++) {
    int c = tid + k * 256;
    valid[k] = (c < 1000);
    muv[k] = valid[k] ? mu[cbase + c]    : 0.f;
    sgv[k] = valid[k] ? sigma[cbase + c] : 0.f;
    prob[k] = 0.f;
  }

  for (int t = 0; t < 16; t++) {
    float pA = 0.f, pB = 0.f;
    float eA[4], eB[4];
    unsigned ibase = (unsigned)(t * 4096000 + cbase);
    for (int k = 0; k < 4; k++) {
      eA[k] = 0.f; eB[k] = 0.f;
      if (valid[k]) {
        unsigned i0 = ibase + (unsigned)(tid + k * 256);
        unsigned o0, o1;
        threefry(i0, i0 + H_HALF, o0, o1);
        float epsA = normal_from_u(bits_to_u(o0));   // sample t
        float epsB = normal_from_u(bits_to_u(o1));   // sample t+16
        eA[k] = __expf(fmaf(sgv[k], epsA, muv[k]));
        eB[k] = __expf(fmaf(sgv[k], epsB, muv[k]));
        pA += eA[k]; pB += eB[k];
      }
    }
    // wave reduce both sums
    for (int m = 1; m < 64; m <<= 1) {
      pA += __shfl_xor(pA, m, 64);
      pB += __shfl_xor(pB, m, 64);
    }
    __syncthreads();                       // protect LDS from prev iter reads
    if (lane == 0) { redA[w] = pA; redB[w] = pB; }
    __syncthreads();
    float SA = redA[0] + redA[1] + redA[2] + redA[3];
    float SB = redB[0] + redB[1] + redB[2] + redB[3];
    float rA = 1.0f / SA, rB = 1.0f / SB;
    for (int k = 0; k < 4; k++)
      prob[k] = fmaf(eA[k], rA, fmaf(eB[k], rB, prob[k]));
  }

  for (int k = 0; k < 4; k++) {
    int c = tid + k * 256;
    if (valid[k]) out0[cbase + c] = __expf(prob[k] * 0.03125f);
  }
}

// ---------------- launch ----------------
extern "C" void kernel_launch(void* const* d_in, const int* in_sizes, int n_in,
                              void* d_out, int out_size, void* d_ws, size_t ws_size,
                              hipStream_t stream) {
  const float* x = (const float*)d_in[0];   // 4096*1024
  const float* W = (const float*)d_in[1];   // 2000*1024
  float* out = (float*)d_out;               // [mu_out | sigma], each 4096000

  // ws layout
  unsigned short* xbf = (unsigned short*)d_ws;                        //  8,388,608 B
  unsigned short* wbf = (unsigned short*)((char*)d_ws + 8388608);     //  4,194,304 B
  float*          mu  = (float*)((char*)d_ws + 12582912);             // 16,384,000 B
  float* sigma = out + NC_TOT;

  convert_kernel<<<6144, 256, 0, stream>>>(x, W, xbf, wbf);
  dim3 g2(16, 32);
  gemm_kernel<<<g2, 256, 0, stream>>>(xbf, wbf, mu, sigma);
  sample_kernel<<<4096, 256, 0, stream>>>(mu, sigma, out);
}

// Round 2
// 291.296 us; speedup vs baseline: 1.3143x; 1.3143x over previous
//
#include <hip/hip_runtime.h>

// Problem: N=4096, D=1024, C=1000, T=32
//   h = x @ W^T  (4096 x 2000), mu = h[:, :1000], logvar = h[:, 1000:]
//   sigma = exp(0.5*logvar)
//   eps = jax.random.normal(key(42), (32,4096,1000))  -- threefry2x32, bit-exact
//   prob = mean_t softmax(mu + sigma*eps), out0 = exp(prob), out1 = sigma

typedef __attribute__((ext_vector_type(8))) _Float16 f16x8;
typedef __attribute__((ext_vector_type(4))) float f32x4;
typedef __attribute__((ext_vector_type(2))) float f32x2;

#define NC_TOT  4096000
#define H_HALF  65536000u   // half of T*N*C = 131072000

// ---------------- fp32 -> fp16 (RNE; |x|max ~5.5, no overflow) ----------------
__device__ __forceinline__ unsigned short f2h(float f) {
  _Float16 h = (_Float16)f;                       // v_cvt_f16_f32, RTNE
  return __builtin_bit_cast(unsigned short, h);
}

// x: 4096x1024 fp32 -> fp16; W: 2000x1024 fp32 -> fp16 padded to 2048 rows (zeros)
__global__ __launch_bounds__(256) void convert_kernel(
    const float* __restrict__ x, const float* __restrict__ W,
    unsigned short* __restrict__ xh, unsigned short* __restrict__ wh) {
  int qid = blockIdx.x * 256 + threadIdx.x;   // one float4 per thread
  if (qid < 1048576) {                        // x: 4096*1024/4
    float4 v = ((const float4*)x)[qid];
    ushort4 o = make_ushort4(f2h(v.x), f2h(v.y), f2h(v.z), f2h(v.w));
    ((ushort4*)xh)[qid] = o;
  } else {
    int q = qid - 1048576;                    // padded W quad index, < 524288
    int row = q >> 8;
    ushort4 o;
    if (row < 2000) {
      float4 v = ((const float4*)W)[q];
      o = make_ushort4(f2h(v.x), f2h(v.y), f2h(v.z), f2h(v.w));
    } else {
      o = make_ushort4(0, 0, 0, 0);
    }
    ((ushort4*)wh)[q] = o;
  }
}

// ---------------- fp16 MFMA GEMM: h = x @ W^T ----------------
// 128x128 tile, BK=32, 256 thr = 4 waves, each wave 64x64 = 4x4 MFMA 16x16x32.
#define BK  32
#define LDK 40   // padded LDS k-stride (elems)

__global__ __launch_bounds__(256) void gemm_kernel(
    const unsigned short* __restrict__ Ah,    // [4096][1024] fp16 bits
    const unsigned short* __restrict__ Bh,    // [2048][1024] fp16 bits, padded
    float* __restrict__ mu,                   // [4096][1000]
    float* __restrict__ sigma_out) {          // d_out + NC_TOT
  const int K = 1024;
  __shared__ unsigned short As[128 * LDK];
  __shared__ unsigned short Bs[128 * LDK];

  int tid  = threadIdx.x;
  int bx   = blockIdx.x;          // 0..15 (col tiles, padded 2048)
  int by   = blockIdx.y;          // 0..31 (row tiles, M=4096)
  int w    = tid >> 6;
  int lane = tid & 63;
  int wr   = (w >> 1) * 64;
  int wc   = (w & 1) * 64;
  int lrow = lane & 15;
  int kq   = lane >> 4;

  f32x4 acc[4][4];
  for (int i = 0; i < 4; i++)
    for (int j = 0; j < 4; j++) acc[i][j] = (f32x4){0.f, 0.f, 0.f, 0.f};

  int srow = tid >> 2;
  int sq   = tid & 3;
  int aBase = (by * 128) * K;
  int bBase = (bx * 128) * K;

  for (int kk = 0; kk < K; kk += BK) {
    uint4 av0 = *(const uint4*)(Ah + aBase + srow * K        + kk + sq * 8);
    uint4 av1 = *(const uint4*)(Ah + aBase + (srow + 64) * K + kk + sq * 8);
    uint4 bv0 = *(const uint4*)(Bh + bBase + srow * K        + kk + sq * 8);
    uint4 bv1 = *(const uint4*)(Bh + bBase + (srow + 64) * K + kk + sq * 8);
    __syncthreads();
    *(uint4*)(As + srow * LDK        + sq * 8) = av0;
    *(uint4*)(As + (srow + 64) * LDK + sq * 8) = av1;
    *(uint4*)(Bs + srow * LDK        + sq * 8) = bv0;
    *(uint4*)(Bs + (srow + 64) * LDK + sq * 8) = bv1;
    __syncthreads();

    f16x8 a[4], b[4];
    for (int i = 0; i < 4; i++)
      a[i] = *(const f16x8*)(As + (wr + i * 16 + lrow) * LDK + kq * 8);
    for (int j = 0; j < 4; j++)
      b[j] = *(const f16x8*)(Bs + (wc + j * 16 + lrow) * LDK + kq * 8);
    for (int i = 0; i < 4; i++)
      for (int j = 0; j < 4; j++)
        acc[i][j] = __builtin_amdgcn_mfma_f32_16x16x32_f16(a[i], b[j], acc[i][j], 0, 0, 0);
  }

  // C/D layout: col = lane&15 (N), row = (lane>>4)*4 + reg (M)
  int orow0 = by * 128 + wr + (lane >> 4) * 4;
  int ocol0 = bx * 128 + wc + (lane & 15);
  for (int i = 0; i < 4; i++) {
    for (int j = 0; j < 4; j++) {
      int c = ocol0 + j * 16;
      for (int v = 0; v < 4; v++) {
        int r = orow0 + i * 16 + v;
        float val = acc[i][j][v];
        if (c < 1000)       mu[r * 1000 + c] = val;
        else if (c < 2000)  sigma_out[r * 1000 + (c - 1000)] = __expf(0.5f * val);
      }
    }
  }
}

// ---------------- threefry2x32, key = (0, 42) ----------------
__device__ __forceinline__ void threefry(unsigned x0, unsigned x1,
                                         unsigned& o0, unsigned& o1) {
  const unsigned ks1 = 42u;
  const unsigned ks2 = 0x1BD11BDAu ^ 42u;
#define TF_RND(r) { x0 += x1; x1 = (x1 << (r)) | (x1 >> (32 - (r))); x1 ^= x0; }
  x1 += ks1;
  TF_RND(13) TF_RND(15) TF_RND(26) TF_RND(6)
  x0 += ks1;  x1 += ks2 + 1u;
  TF_RND(17) TF_RND(29) TF_RND(16) TF_RND(24)
  x0 += ks2;  x1 += 2u;
  TF_RND(13) TF_RND(15) TF_RND(26) TF_RND(6)
  x1 += ks1 + 3u;
  TF_RND(17) TF_RND(29) TF_RND(16) TF_RND(24)
  x0 += ks1;  x1 += ks2 + 4u;
  TF_RND(13) TF_RND(15) TF_RND(26) TF_RND(6)
  x0 += ks2;  x1 += 5u;
#undef TF_RND
  o0 = x0; o1 = x1;
}

// rare-path erfinv tail (w >= 5), identical math to round-1 scalar version
__device__ __forceinline__ float erfinv_big(float x, float w) {
  float v = __fsqrt_rn(w) - 3.0f;
  float p = -0.000200214257f;
  p = fmaf(p, v, 0.000100950558f);
  p = fmaf(p, v, 0.00134934322f);
  p = fmaf(p, v, -0.00367342844f);
  p = fmaf(p, v, 0.00573950773f);
  p = fmaf(p, v, -0.0076224613f);
  p = fmaf(p, v, 0.00943887047f);
  p = fmaf(p, v, 1.00167406f);
  p = fmaf(p, v, 2.83297682f);
  return 1.41421356f * (p * x);
}

__device__ __forceinline__ f32x2 splat2(float c) { return (f32x2){c, c}; }

// packed sqrt(2)*erfinv over both samples; common path uses v_pk_* ops,
// per-component results bit-identical to the round-1 scalar pipeline
__device__ __forceinline__ f32x2 normal2(f32x2 x) {
  f32x2 t = __builtin_elementwise_fma(-x, x, splat2(1.0f));  // 1 - x*x (fma)
  f32x2 lg;
  lg.x = __builtin_amdgcn_logf(t.x);                         // v_log_f32 (log2)
  lg.y = __builtin_amdgcn_logf(t.y);
  f32x2 w = lg * splat2(-0.69314718f);                       // w = -ln(t)
  f32x2 v = w - splat2(2.5f);
  f32x2 p = splat2(2.81022636e-08f);
  p = __builtin_elementwise_fma(p, v, splat2(3.43273939e-07f));
  p = __builtin_elementwise_fma(p, v, splat2(-3.5233877e-06f));
  p = __builtin_elementwise_fma(p, v, splat2(-4.39150654e-06f));
  p = __builtin_elementwise_fma(p, v, splat2(0.00021858087f));
  p = __builtin_elementwise_fma(p, v, splat2(-0.00125372503f));
  p = __builtin_elementwise_fma(p, v, splat2(-0.00417768164f));
  p = __builtin_elementwise_fma(p, v, splat2(0.246640727f));
  p = __builtin_elementwise_fma(p, v, splat2(1.50140941f));
  f32x2 r = (p * x) * splat2(1.41421356f);
  if (w.x >= 5.0f) r.x = erfinv_big(x.x, w.x);               // rare (~0.34%/sample)
  if (w.y >= 5.0f) r.y = erfinv_big(x.y, w.y);
  return r;
}

// bits -> uniform(-0.99999994, 1), packed; per-component identical to round 1
__device__ __forceinline__ f32x2 bits_to_u2(unsigned b0, unsigned b1) {
  f32x2 f;
  f.x = __builtin_bit_cast(float, (b0 >> 9) | 0x3f800000u);
  f.y = __builtin_bit_cast(float, (b1 >> 9) | 0x3f800000u);
  f = f - splat2(1.0f);
  f32x2 u = __builtin_elementwise_fma(f, splat2(2.0f), splat2(-0.99999994f));
  return __builtin_elementwise_max(u, splat2(-0.99999994f));
}

// ---------------- sampling: 1 block per row n; wave w owns t-pairs w*4..w*4+3,
// each wave covers all 1000 c in 16 register-resident chunks of 64.
// eps flat idx = t*4096000 + n*1000 + c; hash pair (i, i+H) -> eps(t), eps(t+16)
__global__ __launch_bounds__(256) void sample_kernel(
    const float* __restrict__ mu,      // ws
    const float* __restrict__ sigma,   // d_out + NC
    float* __restrict__ out0) {        // d_out
  int n    = blockIdx.x;
  int tid  = threadIdx.x;
  int lane = tid & 63, w = tid >> 6;
  __shared__ float pbuf[4][1024];

  int cb = n * 1000;
  float muv[16], sgv[16], prob[16];
#pragma unroll
  for (int j = 0; j < 16; j++) {
    int c = j * 64 + lane;
    bool val = (c < 1000);
    muv[j] = val ? mu[cb + c]    : 0.f;
    sgv[j] = val ? sigma[cb + c] : 0.f;
    prob[j] = 0.f;
  }

  float eA[16], eB[16];
#pragma unroll 1
  for (int it = 0; it < 4; it++) {
    int t = w * 4 + it;
    unsigned ib = (unsigned)(t * 4096000 + cb) + (unsigned)lane;
    float sA = 0.f, sB = 0.f;
#pragma unroll
    for (int j = 0; j < 16; j++) {
      unsigned i0 = ib + (unsigned)(j * 64);
      unsigned o0, o1;
      threefry(i0, i0 + H_HALF, o0, o1);
      f32x2 eps = normal2(bits_to_u2(o0, o1));
      float a = __expf(fmaf(sgv[j], eps.x, muv[j]));   // sample t
      float b = __expf(fmaf(sgv[j], eps.y, muv[j]));   // sample t+16
      if (j == 15) {                                    // c >= 1000 tail
        a = (lane < 40) ? a : 0.f;
        b = (lane < 40) ? b : 0.f;
      }
      eA[j] = a; eB[j] = b;
      sA += a; sB += b;
    }
    // wave-level butterfly reduce of both softmax denominators
#pragma unroll
    for (int m = 1; m < 64; m <<= 1) {
      sA += __shfl_xor(sA, m, 64);
      sB += __shfl_xor(sB, m, 64);
    }
    float rA = 1.0f / sA, rB = 1.0f / sB;
#pragma unroll
    for (int j = 0; j < 16; j++)
      prob[j] = fmaf(eA[j], rA, fmaf(eB[j], rB, prob[j]));
  }

  // combine the 4 waves' partial prob sums (one barrier total)
#pragma unroll
  for (int j = 0; j < 16; j++)
    pbuf[w][j * 64 + lane] = prob[j];
  __syncthreads();
#pragma unroll
  for (int k = 0; k < 4; k++) {
    int c = tid + k * 256;
    if (c < 1000) {
      float s = pbuf[0][c] + pbuf[1][c] + pbuf[2][c] + pbuf[3][c];
      out0[cb + c] = __expf(s * 0.03125f);
    }
  }
}

// ---------------- launch ----------------
extern "C" void kernel_launch(void* const* d_in, const int* in_sizes, int n_in,
                              void* d_out, int out_size, void* d_ws, size_t ws_size,
                              hipStream_t stream) {
  const float* x = (const float*)d_in[0];   // 4096*1024
  const float* W = (const float*)d_in[1];   // 2000*1024
  float* out = (float*)d_out;               // [mu_out | sigma], each 4096000

  unsigned short* xh = (unsigned short*)d_ws;                        //  8,388,608 B
  unsigned short* wh = (unsigned short*)((char*)d_ws + 8388608);     //  4,194,304 B
  float*          mu = (float*)((char*)d_ws + 12582912);             // 16,384,000 B
  float* sigma = out + NC_TOT;

  convert_kernel<<<6144, 256, 0, stream>>>(x, W, xh, wh);
  dim3 g2(16, 32);
  gemm_kernel<<<g2, 256, 0, stream>>>(xh, wh, mu, sigma);
  sample_kernel<<<4096, 256, 0, stream>>>(mu, sigma, out);
}

// Round 3
// 289.807 us; speedup vs baseline: 1.3211x; 1.0051x over previous
//
#include <hip/hip_runtime.h>

// Problem: N=4096, D=1024, C=1000, T=32
//   h = x @ W^T  (4096 x 2000), mu = h[:, :1000], logvar = h[:, 1000:]
//   sigma = exp(0.5*logvar)
//   eps = jax.random.normal(key(42), (32,4096,1000))  -- threefry2x32, bit-exact
//   prob = mean_t softmax(mu + sigma*eps), out0 = exp(prob), out1 = sigma

typedef __attribute__((ext_vector_type(8))) _Float16 f16x8;
typedef __attribute__((ext_vector_type(4))) float f32x4;
typedef __attribute__((ext_vector_type(2))) float f32x2;

#define NC_TOT  4096000
#define H_HALF  65536000u   // half of T*N*C = 131072000

// ---------------- fp32 -> fp16 (RNE; |h-inputs| small, no overflow) ----------------
__device__ __forceinline__ unsigned short f2h(float f) {
  _Float16 h = (_Float16)f;
  return __builtin_bit_cast(unsigned short, h);
}

__global__ __launch_bounds__(256) void convert_kernel(
    const float* __restrict__ x, const float* __restrict__ W,
    unsigned short* __restrict__ xh, unsigned short* __restrict__ wh) {
  int qid = blockIdx.x * 256 + threadIdx.x;
  if (qid < 1048576) {                        // x: 4096*1024/4
    float4 v = ((const float4*)x)[qid];
    ((ushort4*)xh)[qid] = make_ushort4(f2h(v.x), f2h(v.y), f2h(v.z), f2h(v.w));
  } else {
    int q = qid - 1048576;                    // padded W quad index, < 524288
    int row = q >> 8;
    ushort4 o;
    if (row < 2000) {
      float4 v = ((const float4*)W)[q];
      o = make_ushort4(f2h(v.x), f2h(v.y), f2h(v.z), f2h(v.w));
    } else {
      o = make_ushort4(0, 0, 0, 0);
    }
    ((ushort4*)wh)[q] = o;
  }
}

// ---------------- fp16 MFMA GEMM, m97 structure ----------------
// 128x128 tile, BK=32, global_load_lds width=16, unpadded LDS (lane-contiguous).
#define BK 32

typedef __attribute__((address_space(3))) unsigned char lds_byte;
typedef __attribute__((address_space(1))) unsigned char glb_byte;

__device__ __forceinline__ void glds16(const unsigned short* g, unsigned short* l) {
  __builtin_amdgcn_global_load_lds((const glb_byte*)g, (lds_byte*)l, 16, 0, 0);
}

__global__ __launch_bounds__(256) void gemm_kernel(
    const unsigned short* __restrict__ Ah,    // [4096][1024] fp16 bits
    const unsigned short* __restrict__ Bh,    // [2048][1024] fp16 bits, padded
    float* __restrict__ mu,                   // [4096][1000]
    float* __restrict__ sigma_out) {          // d_out + NC_TOT
  const int K = 1024;
  __shared__ unsigned short As[128 * BK];     // 8 KB, row-major [row][k], no pad
  __shared__ unsigned short Bs[128 * BK];

  int tid  = threadIdx.x;
  int bx   = blockIdx.x;          // 0..15 col tiles (padded 2048)
  int by   = blockIdx.y;          // 0..31 row tiles
  int w    = tid >> 6;
  int lane = tid & 63;
  int wr   = (w >> 1) * 64;
  int wc   = (w & 1) * 64;
  int lrow = lane & 15;
  int kq   = lane >> 4;

  f32x4 acc[4][4];
  for (int i = 0; i < 4; i++)
    for (int j = 0; j < 4; j++) acc[i][j] = (f32x4){0.f, 0.f, 0.f, 0.f};

  // staging: wave w stages rows [w*16, w*16+16) (+64 for chunk 1);
  // lane's 16B lands at LDS elem offset w*512 + lane*8  (wave-uniform base + lane*16B)
  int srow = w * 16 + (lane >> 2);
  int scol = (lane & 3) * 8;
  const unsigned short* Ap = Ah + (by * 128 + srow) * K + scol;
  const unsigned short* Bp = Bh + (bx * 128 + srow) * K + scol;
  unsigned short* lA = As + w * 512;          // wave-uniform
  unsigned short* lB = Bs + w * 512;

  for (int kk = 0; kk < K; kk += BK) {
    __syncthreads();                          // prior MFMA reads done
    glds16(Ap + kk,            lA);           // rows w*16..w*16+15
    glds16(Ap + kk + 64 * K,   lA + 2048);    // rows +64
    glds16(Bp + kk,            lB);
    glds16(Bp + kk + 64 * K,   lB + 2048);
    __syncthreads();                          // drains vmcnt -> LDS ready

    f16x8 a[4], b[4];
    for (int i = 0; i < 4; i++)
      a[i] = *(const f16x8*)(As + (wr + i * 16 + lrow) * BK + kq * 8);
    for (int j = 0; j < 4; j++)
      b[j] = *(const f16x8*)(Bs + (wc + j * 16 + lrow) * BK + kq * 8);
    for (int i = 0; i < 4; i++)
      for (int j = 0; j < 4; j++)
        acc[i][j] = __builtin_amdgcn_mfma_f32_16x16x32_f16(a[i], b[j], acc[i][j], 0, 0, 0);
  }

  // C/D layout: col = lane&15 (N), row = (lane>>4)*4 + reg (M)
  int orow0 = by * 128 + wr + (lane >> 4) * 4;
  int ocol0 = bx * 128 + wc + (lane & 15);
  for (int i = 0; i < 4; i++) {
    for (int j = 0; j < 4; j++) {
      int c = ocol0 + j * 16;
      for (int v = 0; v < 4; v++) {
        int r = orow0 + i * 16 + v;
        float val = acc[i][j][v];
        if (c < 1000)       mu[r * 1000 + c] = val;
        else if (c < 2000)  sigma_out[r * 1000 + (c - 1000)] = __expf(0.5f * val);
      }
    }
  }
}

// ---------------- threefry2x32, key = (0, 42) ----------------
__device__ __forceinline__ void threefry(unsigned x0, unsigned x1,
                                         unsigned& o0, unsigned& o1) {
  const unsigned ks1 = 42u;
  const unsigned ks2 = 0x1BD11BDAu ^ 42u;
#define TF_RND(r) { x0 += x1; x1 = (x1 << (r)) | (x1 >> (32 - (r))); x1 ^= x0; }
  x1 += ks1;
  TF_RND(13) TF_RND(15) TF_RND(26) TF_RND(6)
  x0 += ks1;  x1 += ks2 + 1u;
  TF_RND(17) TF_RND(29) TF_RND(16) TF_RND(24)
  x0 += ks2;  x1 += 2u;
  TF_RND(13) TF_RND(15) TF_RND(26) TF_RND(6)
  x1 += ks1 + 3u;
  TF_RND(17) TF_RND(29) TF_RND(16) TF_RND(24)
  x0 += ks1;  x1 += ks2 + 4u;
  TF_RND(13) TF_RND(15) TF_RND(26) TF_RND(6)
  x0 += ks2;  x1 += 5u;
#undef TF_RND
  o0 = x0; o1 = x1;
}

// rare-path erfinv tail (w >= 5); identical math as prior rounds
__device__ __forceinline__ float erfinv_big(float x, float w) {
  float v = __fsqrt_rn(w) - 3.0f;
  float p = -0.000200214257f;
  p = fmaf(p, v, 0.000100950558f);
  p = fmaf(p, v, 0.00134934322f);
  p = fmaf(p, v, -0.00367342844f);
  p = fmaf(p, v, 0.00573950773f);
  p = fmaf(p, v, -0.0076224613f);
  p = fmaf(p, v, 0.00943887047f);
  p = fmaf(p, v, 1.00167406f);
  p = fmaf(p, v, 2.83297682f);
  return 1.41421356f * (p * x);
}

__device__ __forceinline__ f32x2 splat2(float c) { return (f32x2){c, c}; }

__device__ __forceinline__ f32x2 normal2(f32x2 x) {
  f32x2 t = __builtin_elementwise_fma(-x, x, splat2(1.0f));
  f32x2 lg;
  lg.x = __builtin_amdgcn_logf(t.x);
  lg.y = __builtin_amdgcn_logf(t.y);
  f32x2 w = lg * splat2(-0.69314718f);
  f32x2 v = w - splat2(2.5f);
  f32x2 p = splat2(2.81022636e-08f);
  p = __builtin_elementwise_fma(p, v, splat2(3.43273939e-07f));
  p = __builtin_elementwise_fma(p, v, splat2(-3.5233877e-06f));
  p = __builtin_elementwise_fma(p, v, splat2(-4.39150654e-06f));
  p = __builtin_elementwise_fma(p, v, splat2(0.00021858087f));
  p = __builtin_elementwise_fma(p, v, splat2(-0.00125372503f));
  p = __builtin_elementwise_fma(p, v, splat2(-0.00417768164f));
  p = __builtin_elementwise_fma(p, v, splat2(0.246640727f));
  p = __builtin_elementwise_fma(p, v, splat2(1.50140941f));
  f32x2 r = (p * x) * splat2(1.41421356f);
  if (w.x >= 5.0f) r.x = erfinv_big(x.x, w.x);   // rare (~0.34%/sample)
  if (w.y >= 5.0f) r.y = erfinv_big(x.y, w.y);
  return r;
}

// bits -> uniform; max(u,lo) dropped: u = fma(f,2,lo) >= lo always (monotone
// rounding, equality at f=0), so removal is bit-identical.
__device__ __forceinline__ f32x2 bits_to_u2(unsigned b0, unsigned b1) {
  f32x2 f;
  f.x = __builtin_bit_cast(float, (b0 >> 9) | 0x3f800000u);
  f.y = __builtin_bit_cast(float, (b1 >> 9) | 0x3f800000u);
  f = f - splat2(1.0f);
  return __builtin_elementwise_fma(f, splat2(2.0f), splat2(-0.99999994f));
}

// ---------------- sampling ----------------
// 1 block per row n; wave w owns t-pairs w*4..w*4+3; 16 chunks of 64 classes.
// launch_bounds(256,4): allow 128 VGPRs so the scheduler keeps several
// independent threefry chains in flight instead of starving at 52 VGPRs.
__global__ __launch_bounds__(256, 4) void sample_kernel(
    const float* __restrict__ mu,      // ws
    const float* __restrict__ sigma,   // d_out + NC
    float* __restrict__ out0) {        // d_out
  int n    = blockIdx.x;
  int tid  = threadIdx.x;
  int lane = tid & 63, w = tid >> 6;
  __shared__ float pbuf[4][1024];

  int cb = n * 1000;
  float muv[16], sgv[16], prob[16];
#pragma unroll
  for (int j = 0; j < 16; j++) {
    int c = j * 64 + lane;
    bool val = (c < 1000);
    muv[j] = val ? mu[cb + c]    : 0.f;
    sgv[j] = val ? sigma[cb + c] : 0.f;
    prob[j] = 0.f;
  }

  f32x2 e[16];
#pragma unroll 1
  for (int it = 0; it < 4; it++) {
    int t = w * 4 + it;
    unsigned ib = (unsigned)(t * 4096000 + cb) + (unsigned)lane;
    f32x2 s = splat2(0.f);
#pragma unroll
    for (int j = 0; j < 16; j++) {
      unsigned i0 = ib + (unsigned)(j * 64);
      unsigned o0, o1;
      threefry(i0, i0 + H_HALF, o0, o1);
      f32x2 eps = normal2(bits_to_u2(o0, o1));
      // logit = mu + sigma*eps for samples t (.x) and t+16 (.y), packed fma
      f32x2 lg = __builtin_elementwise_fma(splat2(sgv[j]), eps, splat2(muv[j]));
      f32x2 ev;
      ev.x = __expf(lg.x);
      ev.y = __expf(lg.y);
      if (j == 15) {                  // classes >= 1000 are padding
        ev.x = (lane < 40) ? ev.x : 0.f;
        ev.y = (lane < 40) ? ev.y : 0.f;
      }
      e[j] = ev;
      s = s + ev;
    }
#pragma unroll
    for (int m = 1; m < 64; m <<= 1) {
      s.x += __shfl_xor(s.x, m, 64);
      s.y += __shfl_xor(s.y, m, 64);
    }
    float rA = 1.0f / s.x, rB = 1.0f / s.y;
#pragma unroll
    for (int j = 0; j < 16; j++)
      prob[j] = fmaf(e[j].x, rA, fmaf(e[j].y, rB, prob[j]));
  }

#pragma unroll
  for (int j = 0; j < 16; j++)
    pbuf[w][j * 64 + lane] = prob[j];
  __syncthreads();
#pragma unroll
  for (int k = 0; k < 4; k++) {
    int c = tid + k * 256;
    if (c < 1000) {
      float sm = pbuf[0][c] + pbuf[1][c] + pbuf[2][c] + pbuf[3][c];
      out0[cb + c] = __expf(sm * 0.03125f);
    }
  }
}

// ---------------- launch ----------------
extern "C" void kernel_launch(void* const* d_in, const int* in_sizes, int n_in,
                              void* d_out, int out_size, void* d_ws, size_t ws_size,
                              hipStream_t stream) {
  const float* x = (const float*)d_in[0];   // 4096*1024
  const float* W = (const float*)d_in[1];   // 2000*1024
  float* out = (float*)d_out;               // [mu_out | sigma], each 4096000

  unsigned short* xh = (unsigned short*)d_ws;                        //  8,388,608 B
  unsigned short* wh = (unsigned short*)((char*)d_ws + 8388608);     //  4,194,304 B
  float*          mu = (float*)((char*)d_ws + 12582912);             // 16,384,000 B
  float* sigma = out + NC_TOT;

  convert_kernel<<<6144, 256, 0, stream>>>(x, W, xh, wh);
  dim3 g2(16, 32);
  gemm_kernel<<<g2, 256, 0, stream>>>(xh, wh, mu, sigma);
  sample_kernel<<<4096, 256, 0, stream>>>(mu, sigma, out);
}